// Round 1
// baseline (39433.224 us; speedup 1.0000x reference)
//
#include <hip/hip_runtime.h>
#include <hip/hip_bf16.h>
#include <math.h>

// Problem constants
constexpr int NB  = 32;     // batch
constexpr int NS  = 256;    // seq len
constexpr int NE  = 1024;   // embed dim
constexpr int NH  = 1024;   // LSTM output dim (2*NHD)
constexpr int NHD = 512;    // per-direction hidden
constexpr int NG  = 2048;   // 4*NHD gates
constexpr int NP  = 16;     // prompt positions
constexpr int NBS = NB * NS; // 8192 rows
constexpr int GK  = 1024;   // GEMM K (= NE = NH)

__device__ __forceinline__ float sigm(float x) { return 1.0f / (1.0f + __expf(-x)); }

// ---------------------------------------------------------------------------
// Transpose Whh [2][2048][512] -> WhhT [2][512][2048] for coalesced reads
// ---------------------------------------------------------------------------
__global__ void k_transpose(const float* __restrict__ src, float* __restrict__ dst) {
    int idx = blockIdx.x * 256 + threadIdx.x;      // over 2*512*2048
    int d   = idx / (NHD * NG);
    int rem = idx % (NHD * NG);
    int k   = rem / NG;
    int j   = rem % NG;
    dst[idx] = src[((size_t)d * NG + j) * NHD + k];
}

// ---------------------------------------------------------------------------
// allb[b,s,:] = emb[id]+ctx[id], overwritten by prompt_emb at prompt slots
// (written into d_out, reused as scratch during layer 0)
// ---------------------------------------------------------------------------
__global__ void k_allb(const float* __restrict__ emb, const float* __restrict__ ctx,
                       const float* __restrict__ pemb, const int* __restrict__ ids,
                       const int* __restrict__ pidx, float* __restrict__ allb) {
    int r = blockIdx.x;            // row = b*NS + s
    int b = r >> 8, s = r & 255;
    __shared__ int ppos;
    if (threadIdx.x == 0) {
        int t = -1;
        #pragma unroll
        for (int p = 0; p < NP; ++p)
            if (pidx[b * NP + p] == s) t = p;
        ppos = t;
    }
    __syncthreads();
    int e = threadIdx.x;           // 256 threads x float4 = 1024 floats
    float4 v;
    if (ppos >= 0) {
        v = ((const float4*)(pemb + (size_t)ppos * NE))[e];
    } else {
        int id = ids[r];
        float4 a = ((const float4*)(emb + (size_t)id * NE))[e];
        float4 c = ((const float4*)(ctx + (size_t)id * NE))[e];
        v = make_float4(a.x + c.x, a.y + c.y, a.z + c.z, a.w + c.w);
    }
    ((float4*)(allb + (size_t)r * NE))[e] = v;
}

// ---------------------------------------------------------------------------
// d_out[b,s,:] = emb[ids[b,s]]   (the "raw" base of the final output)
// ---------------------------------------------------------------------------
__global__ void k_raw(const float* __restrict__ emb, const int* __restrict__ ids,
                      float* __restrict__ out) {
    int r = blockIdx.x;
    int id = ids[r];
    ((float4*)(out + (size_t)r * NE))[threadIdx.x] =
        ((const float4*)(emb + (size_t)id * NE))[threadIdx.x];
}

// ---------------------------------------------------------------------------
// C[M=8192, N=2048] = A[M,1024] @ W[2048,1024]^T + (bih+bhh)
// 64x64 tile, 256 threads, 4x4 per thread, fp32
// ---------------------------------------------------------------------------
__global__ __launch_bounds__(256) void k_gemm(const float* __restrict__ A,
                                              const float* __restrict__ W,
                                              const float* __restrict__ bih,
                                              const float* __restrict__ bhh,
                                              float* __restrict__ C) {
    __shared__ float As[16][65];
    __shared__ float Ws[16][65];
    int tid = threadIdx.x;
    int tx = tid & 15, ty = tid >> 4;
    int n0 = blockIdx.x * 64, m0 = blockIdx.y * 64;
    int lr = tid >> 2;          // 0..63: row within tile
    int lk = (tid & 3) * 4;     // 0,4,8,12: k within k-tile
    float acc[4][4] = {};
    for (int kt = 0; kt < GK; kt += 16) {
        float4 av = *(const float4*)(A + (size_t)(m0 + lr) * GK + kt + lk);
        float4 wv = *(const float4*)(W + (size_t)(n0 + lr) * GK + kt + lk);
        As[lk + 0][lr] = av.x; As[lk + 1][lr] = av.y;
        As[lk + 2][lr] = av.z; As[lk + 3][lr] = av.w;
        Ws[lk + 0][lr] = wv.x; Ws[lk + 1][lr] = wv.y;
        Ws[lk + 2][lr] = wv.z; Ws[lk + 3][lr] = wv.w;
        __syncthreads();
        #pragma unroll
        for (int kk = 0; kk < 16; ++kk) {
            float a[4], w[4];
            #pragma unroll
            for (int i = 0; i < 4; ++i) a[i] = As[kk][ty * 4 + i];
            #pragma unroll
            for (int j = 0; j < 4; ++j) w[j] = Ws[kk][tx * 4 + j];
            #pragma unroll
            for (int i = 0; i < 4; ++i)
                #pragma unroll
                for (int j = 0; j < 4; ++j) acc[i][j] += a[i] * w[j];
        }
        __syncthreads();
    }
    #pragma unroll
    for (int j = 0; j < 4; ++j) {
        int n = n0 + tx * 4 + j;
        float bias = bih[n] + bhh[n];
        #pragma unroll
        for (int i = 0; i < 4; ++i)
            C[(size_t)(m0 + ty * 4 + i) * NG + n] = acc[i][j] + bias;
    }
}

// ---------------------------------------------------------------------------
// LSTM recurrence, one workgroup per (direction, batch) chain.
// G: [2][8192][2048] precomputed x@Wih.T + bias. WhhT: [2][512][2048].
// hout: [8192][1024], direction d writes columns [d*512, d*512+512).
// Gate order along j: i, f, g, o (PyTorch).
// ---------------------------------------------------------------------------
__global__ __launch_bounds__(256) void k_lstm(const float* __restrict__ G,
                                              const float* __restrict__ WhhT,
                                              float* __restrict__ hout) {
    int blk = blockIdx.x;
    int d = blk & 1, b = blk >> 1;   // interleave dirs across XCDs
    __shared__ float hs[NHD];
    __shared__ float cs[NHD];
    int tid = threadIdx.x;
    hs[tid] = 0.f; hs[tid + 256] = 0.f;
    cs[tid] = 0.f; cs[tid + 256] = 0.f;
    __syncthreads();
    const float* Gd = G + ((size_t)d * NBS + (size_t)b * NS) * NG;
    const float* Wd = WhhT + (size_t)d * NHD * NG;
    for (int step = 0; step < NS; ++step) {
        int tt = d ? (NS - 1 - step) : step;
        const float* grow = Gd + (size_t)tt * NG;
        float acc[8];
        #pragma unroll
        for (int u = 0; u < 8; ++u) acc[u] = grow[tid + 256 * u];
        #pragma unroll 2
        for (int k = 0; k < NHD; ++k) {
            float hk = hs[k];
            const float* wrow = Wd + (size_t)k * NG + tid;
            #pragma unroll
            for (int u = 0; u < 8; ++u) acc[u] += hk * wrow[256 * u];
        }
        __syncthreads();   // all reads of hs done before update
        #pragma unroll
        for (int v = 0; v < 2; ++v) {
            int n = tid + 256 * v;
            float ig = sigm(acc[v]);
            float fg = sigm(acc[2 + v]);
            float gg = tanhf(acc[4 + v]);
            float og = sigm(acc[6 + v]);
            float cn = fg * cs[n] + ig * gg;
            cs[n] = cn;
            float hn = og * tanhf(cn);
            hs[n] = hn;
            hout[(size_t)(b * NS + tt) * NH + d * NHD + n] = hn;
        }
        __syncthreads();   // updates visible before next step's reads
    }
}

// ---------------------------------------------------------------------------
// MLP head at prompt positions only: out[b,idx] = relu(h@W1.T+b1)@W2.T+b2+pemb
// One block per (b,p) row.
// ---------------------------------------------------------------------------
__global__ __launch_bounds__(256) void k_mlp(const float* __restrict__ h1,
                                             const float* __restrict__ W1,
                                             const float* __restrict__ b1,
                                             const float* __restrict__ W2,
                                             const float* __restrict__ b2,
                                             const float* __restrict__ pemb,
                                             const int* __restrict__ pidx,
                                             float* __restrict__ out) {
    int blk = blockIdx.x;
    int b = blk >> 4, p = blk & 15;
    int s = pidx[b * NP + p];
    __shared__ float hrow[NH];
    __shared__ float mid[NH];
    int tid = threadIdx.x;
    ((float4*)hrow)[tid] = ((const float4*)(h1 + (size_t)(b * NS + s) * NH))[tid];
    __syncthreads();
    #pragma unroll
    for (int u = 0; u < 4; ++u) {
        int j = tid + 256 * u;
        const float4* wr = (const float4*)(W1 + (size_t)j * NH);
        const float4* hr = (const float4*)hrow;
        float acc = b1[j];
        for (int k = 0; k < NH / 4; ++k) {
            float4 w = wr[k], x = hr[k];
            acc += w.x * x.x + w.y * x.y + w.z * x.z + w.w * x.w;
        }
        mid[j] = fmaxf(acc, 0.f);
    }
    __syncthreads();
    #pragma unroll
    for (int u = 0; u < 4; ++u) {
        int j = tid + 256 * u;
        const float4* wr = (const float4*)(W2 + (size_t)j * NH);
        const float4* mr = (const float4*)mid;
        float acc = b2[j];
        for (int k = 0; k < NH / 4; ++k) {
            float4 w = wr[k], x = mr[k];
            acc += w.x * x.x + w.y * x.y + w.z * x.z + w.w * x.w;
        }
        out[(size_t)(b * NS + s) * NE + j] = acc + pemb[(size_t)p * NE + j];
    }
}

// ---------------------------------------------------------------------------
extern "C" void kernel_launch(void* const* d_in, const int* in_sizes, int n_in,
                              void* d_out, int out_size, void* d_ws, size_t ws_size,
                              hipStream_t stream) {
    const float* emb  = (const float*)d_in[0];
    const float* ctx  = (const float*)d_in[1];
    const float* pemb = (const float*)d_in[2];
    const float* Wih0 = (const float*)d_in[3];
    const float* Whh0 = (const float*)d_in[4];
    const float* bih0 = (const float*)d_in[5];
    const float* bhh0 = (const float*)d_in[6];
    const float* Wih1 = (const float*)d_in[7];
    const float* Whh1 = (const float*)d_in[8];
    const float* bih1 = (const float*)d_in[9];
    const float* bhh1 = (const float*)d_in[10];
    const float* W1   = (const float*)d_in[11];
    const float* b1   = (const float*)d_in[12];
    const float* W2   = (const float*)d_in[13];
    const float* b2   = (const float*)d_in[14];
    const int* ids    = (const int*)d_in[15];
    const int* pidx   = (const int*)d_in[16];
    float* out = (float*)d_out;

    // Workspace layout (bytes):
    //   G:     [2][8192][2048] fp32 = 134217728
    //   hbuf:  [8192][1024]    fp32 =  33554432  (h0, then overwritten by h1)
    //   WT0:   [2][512][2048]  fp32 =   8388608
    //   WT1:   [2][512][2048]  fp32 =   8388608
    // total = 184549376 (176 MiB)
    char* ws = (char*)d_ws;
    float* G    = (float*)ws;
    float* hbuf = (float*)(ws + 134217728u);
    float* WT0  = (float*)(ws + 134217728u + 33554432u);
    float* WT1  = (float*)(ws + 134217728u + 33554432u + 8388608u);

    float* allb = out;   // reuse d_out as layer-0 input buffer

    k_transpose<<<dim3(8192), dim3(256), 0, stream>>>(Whh0, WT0);
    k_transpose<<<dim3(8192), dim3(256), 0, stream>>>(Whh1, WT1);

    k_allb<<<dim3(NBS), dim3(256), 0, stream>>>(emb, ctx, pemb, ids, pidx, allb);

    // Layer 0 input projections + recurrence
    for (int d = 0; d < 2; ++d)
        k_gemm<<<dim3(NG / 64, NBS / 64), dim3(256), 0, stream>>>(
            allb, Wih0 + (size_t)d * NG * GK, bih0 + d * NG, bhh0 + d * NG,
            G + (size_t)d * NBS * NG);
    k_lstm<<<dim3(64), dim3(256), 0, stream>>>(G, WT0, hbuf);

    // allb no longer needed: restore raw embeddings into d_out
    k_raw<<<dim3(NBS), dim3(256), 0, stream>>>(emb, ids, out);

    // Layer 1
    for (int d = 0; d < 2; ++d)
        k_gemm<<<dim3(NG / 64, NBS / 64), dim3(256), 0, stream>>>(
            hbuf, Wih1 + (size_t)d * NG * GK, bih1 + d * NG, bhh1 + d * NG,
            G + (size_t)d * NBS * NG);
    k_lstm<<<dim3(64), dim3(256), 0, stream>>>(G, WT1, hbuf);

    // MLP head at prompt rows only, overwrite those rows of d_out
    k_mlp<<<dim3(NB * NP), dim3(256), 0, stream>>>(hbuf, W1, b1, W2, b2, pemb, pidx, out);
}

// Round 2
// 21268.802 us; speedup vs baseline: 1.8540x; 1.8540x over previous
//
#include <hip/hip_runtime.h>
#include <hip/hip_bf16.h>
#include <math.h>

// Problem constants
constexpr int NB  = 32;      // batch
constexpr int NS  = 256;     // seq len
constexpr int NE  = 1024;    // embed dim
constexpr int NH  = 1024;    // LSTM output dim (2*NHD)
constexpr int NHD = 512;     // per-direction hidden
constexpr int NG  = 2048;    // 4*NHD gates
constexpr int NP  = 16;      // prompt positions
constexpr int NBS = NB * NS; // 8192 rows
constexpr int GK  = 1024;    // GEMM K (= NE = NH)

// Persistent LSTM decomposition
constexpr int UPW  = 8;          // hidden units per WG
constexpr int NWGD = NHD / UPW;  // 64 WGs per direction
constexpr int NSL  = 16;         // K slices (lanes tid&15)
constexpr int KSL  = NHD / NSL;  // 32 floats of K per thread
constexpr int PSTR = 4 * UPW * NB + 4; // partial slice stride (1028 floats, +4 pad)

__device__ __forceinline__ float sigm(float x) { return 1.0f / (1.0f + __expf(-x)); }

// ---------------------------------------------------------------------------
__global__ void k_zero(int* p) { p[threadIdx.x] = 0; }

// ---------------------------------------------------------------------------
// allb[b,s,:] = emb[id]+ctx[id], overwritten by prompt_emb at prompt slots
// ---------------------------------------------------------------------------
__global__ void k_allb(const float* __restrict__ emb, const float* __restrict__ ctx,
                       const float* __restrict__ pemb, const int* __restrict__ ids,
                       const int* __restrict__ pidx, float* __restrict__ allb) {
    int r = blockIdx.x;            // row = b*NS + s
    int b = r >> 8, s = r & 255;
    __shared__ int ppos;
    if (threadIdx.x == 0) {
        int t = -1;
        #pragma unroll
        for (int p = 0; p < NP; ++p)
            if (pidx[b * NP + p] == s) t = p;
        ppos = t;
    }
    __syncthreads();
    int e = threadIdx.x;
    float4 v;
    if (ppos >= 0) {
        v = ((const float4*)(pemb + (size_t)ppos * NE))[e];
    } else {
        int id = ids[r];
        float4 a = ((const float4*)(emb + (size_t)id * NE))[e];
        float4 c = ((const float4*)(ctx + (size_t)id * NE))[e];
        v = make_float4(a.x + c.x, a.y + c.y, a.z + c.z, a.w + c.w);
    }
    ((float4*)(allb + (size_t)r * NE))[e] = v;
}

// ---------------------------------------------------------------------------
__global__ void k_raw(const float* __restrict__ emb, const int* __restrict__ ids,
                      float* __restrict__ out) {
    int r = blockIdx.x;
    int id = ids[r];
    ((float4*)(out + (size_t)r * NE))[threadIdx.x] =
        ((const float4*)(emb + (size_t)id * NE))[threadIdx.x];
}

// ---------------------------------------------------------------------------
// C[M=8192, N=2048] = A[M,1024] @ W[2048,1024]^T + (bih+bhh), fp32
// ---------------------------------------------------------------------------
__global__ __launch_bounds__(256) void k_gemm(const float* __restrict__ A,
                                              const float* __restrict__ W,
                                              const float* __restrict__ bih,
                                              const float* __restrict__ bhh,
                                              float* __restrict__ C) {
    __shared__ float As[16][65];
    __shared__ float Ws[16][65];
    int tid = threadIdx.x;
    int tx = tid & 15, ty = tid >> 4;
    int n0 = blockIdx.x * 64, m0 = blockIdx.y * 64;
    int lr = tid >> 2;
    int lk = (tid & 3) * 4;
    float acc[4][4] = {};
    for (int kt = 0; kt < GK; kt += 16) {
        float4 av = *(const float4*)(A + (size_t)(m0 + lr) * GK + kt + lk);
        float4 wv = *(const float4*)(W + (size_t)(n0 + lr) * GK + kt + lk);
        As[lk + 0][lr] = av.x; As[lk + 1][lr] = av.y;
        As[lk + 2][lr] = av.z; As[lk + 3][lr] = av.w;
        Ws[lk + 0][lr] = wv.x; Ws[lk + 1][lr] = wv.y;
        Ws[lk + 2][lr] = wv.z; Ws[lk + 3][lr] = wv.w;
        __syncthreads();
        #pragma unroll
        for (int kk = 0; kk < 16; ++kk) {
            float a[4], w[4];
            #pragma unroll
            for (int i = 0; i < 4; ++i) a[i] = As[kk][ty * 4 + i];
            #pragma unroll
            for (int j = 0; j < 4; ++j) w[j] = Ws[kk][tx * 4 + j];
            #pragma unroll
            for (int i = 0; i < 4; ++i)
                #pragma unroll
                for (int j = 0; j < 4; ++j) acc[i][j] += a[i] * w[j];
        }
        __syncthreads();
    }
    #pragma unroll
    for (int j = 0; j < 4; ++j) {
        int n = n0 + tx * 4 + j;
        float bias = bih[n] + bhh[n];
        #pragma unroll
        for (int i = 0; i < 4; ++i)
            C[(size_t)(m0 + ty * 4 + i) * NG + n] = acc[i][j] + bias;
    }
}

// ---------------------------------------------------------------------------
// Persistent barrier-synced LSTM recurrence.
// Grid = 128 WGs: wg&1 = direction, wg>>1 = 8-unit slice (n0 = slice*8).
// Weights resident in VGPRs: thread (rg=tid>>4, s=tid&15) holds rows
// {2rg, 2rg+1} (local row r32 = g*8+u <-> global gate row g*512+n0+u),
// K slice [s*32, s*32+32). h staged in LDS (XOR-swizzled float4 columns:
// col4 c = 8s+m stored at p4 = 8s+(m^(s&7)) -> conflict-free reads).
// Per-direction monotonic spin barrier on ctr[d] each step.
// ---------------------------------------------------------------------------
__global__ __launch_bounds__(256) void k_lstm_p(const float* __restrict__ G,
                                                const float* __restrict__ Whh,
                                                float* __restrict__ hout,
                                                int* __restrict__ ctr) {
    __shared__ float h_lds[NB * NHD];      // 64 KB, swizzled
    __shared__ float part[NSL * PSTR];     // 64.25 KB partial sums
    int wg = blockIdx.x;
    int d = wg & 1;
    int slice = wg >> 1;
    int n0 = slice * UPW;
    int tid = threadIdx.x;
    int s  = tid & 15;        // K slice
    int rg = tid >> 4;        // row group 0..15
    int uB = tid >> 5;        // phase-B unit 0..7
    int bB = tid & 31;        // phase-B batch
    int* ctrd = ctr + d;

    // Load resident weights (Whh layout [2][2048][512], gate-major rows)
    float w0[KSL], w1[KSL];
    {
        int r32 = 2 * rg;
        int g0 = r32 >> 3, u0 = r32 & 7;
        int g1 = (r32 + 1) >> 3, u1 = (r32 + 1) & 7;
        const float* p0 = Whh + ((size_t)d * NG + g0 * NHD + n0 + u0) * NHD + s * KSL;
        const float* p1 = Whh + ((size_t)d * NG + g1 * NHD + n0 + u1) * NHD + s * KSL;
        #pragma unroll
        for (int m = 0; m < KSL / 4; ++m) {
            float4 a = ((const float4*)p0)[m];
            w0[4*m] = a.x; w0[4*m+1] = a.y; w0[4*m+2] = a.z; w0[4*m+3] = a.w;
            float4 b = ((const float4*)p1)[m];
            w1[4*m] = b.x; w1[4*m+1] = b.y; w1[4*m+2] = b.z; w1[4*m+3] = b.w;
        }
    }
    float creg = 0.f;
    const float* Gd = G + (size_t)d * NBS * NG;

    for (int step = 0; step < NS; ++step) {
        int tt = d ? (NS - 1 - step) : step;
        // Prefetch phase-B input-projection gate values (long latency cover)
        float Gv0, Gv1, Gv2, Gv3;
        {
            const float* gp = Gd + (size_t)(bB * NS + tt) * NG + n0 + uB;
            Gv0 = gp[0]; Gv1 = gp[NHD]; Gv2 = gp[2 * NHD]; Gv3 = gp[3 * NHD];
        }
        if (step) {
            // Phase A: partial dot products, 4 batches at a time
            for (int bb = 0; bb < NB; bb += 4) {
                float a00 = 0, a01 = 0, a02 = 0, a03 = 0;
                float a10 = 0, a11 = 0, a12 = 0, a13 = 0;
                const float4* hb0 = (const float4*)(h_lds + (bb + 0) * NHD);
                const float4* hb1 = (const float4*)(h_lds + (bb + 1) * NHD);
                const float4* hb2 = (const float4*)(h_lds + (bb + 2) * NHD);
                const float4* hb3 = (const float4*)(h_lds + (bb + 3) * NHD);
                #pragma unroll
                for (int m = 0; m < 8; ++m) {
                    int p4 = 8 * s + (m ^ (s & 7));
                    float4 h0v = hb0[p4];
                    float4 h1v = hb1[p4];
                    float4 h2v = hb2[p4];
                    float4 h3v = hb3[p4];
#define FMA_B(hv, A0, A1) \
    A0 += w0[4*m]*hv.x + w0[4*m+1]*hv.y + w0[4*m+2]*hv.z + w0[4*m+3]*hv.w; \
    A1 += w1[4*m]*hv.x + w1[4*m+1]*hv.y + w1[4*m+2]*hv.z + w1[4*m+3]*hv.w;
                    FMA_B(h0v, a00, a10)
                    FMA_B(h1v, a01, a11)
                    FMA_B(h2v, a02, a12)
                    FMA_B(h3v, a03, a13)
#undef FMA_B
                }
                int r32 = 2 * rg;
                *(float4*)(part + s * PSTR + r32 * NB + bb)       = make_float4(a00, a01, a02, a03);
                *(float4*)(part + s * PSTR + (r32 + 1) * NB + bb) = make_float4(a10, a11, a12, a13);
            }
        }
        __syncthreads();
        // Phase B: reduce 16 slices, add G row, gate nonlinearity
        float g0 = Gv0, g1 = Gv1, g2 = Gv2, g3 = Gv3;
        if (step) {
            #pragma unroll
            for (int ss = 0; ss < NSL; ++ss) {
                const float* pp = part + ss * PSTR + bB;
                g0 += pp[(0 * UPW + uB) * NB];
                g1 += pp[(1 * UPW + uB) * NB];
                g2 += pp[(2 * UPW + uB) * NB];
                g3 += pp[(3 * UPW + uB) * NB];
            }
        }
        float ig = sigm(g0), fg = sigm(g1), gg = tanhf(g2), og = sigm(g3);
        creg = fg * creg + ig * gg;
        float hv = og * tanhf(creg);
        hout[(size_t)(bB * NS + tt) * NH + d * NHD + n0 + uB] = hv;
        // Device-scope barrier over this direction's 64 WGs
        __threadfence();
        __syncthreads();
        if (tid == 0) {
            __hip_atomic_fetch_add(ctrd, 1, __ATOMIC_ACQ_REL, __HIP_MEMORY_SCOPE_AGENT);
            int target = NWGD * (step + 1);
            while (__hip_atomic_load(ctrd, __ATOMIC_ACQUIRE, __HIP_MEMORY_SCOPE_AGENT) < target)
                __builtin_amdgcn_s_sleep(8);
        }
        __syncthreads();
        __threadfence();
        // Stage full h[32][512] (this step's output) into swizzled LDS
        if (step < NS - 1) {
            int r = tid & 7, bSt = tid >> 3;
            const float4* src = (const float4*)(hout + (size_t)(bSt * NS + tt) * NH + d * NHD);
            float4* dstrow = (float4*)(h_lds + bSt * NHD);
            #pragma unroll
            for (int i = 0; i < 16; ++i) {
                float4 v = src[8 * i + r];
                dstrow[8 * i + (r ^ (i & 7))] = v;
            }
            __syncthreads();
        }
    }
}

// ---------------------------------------------------------------------------
// MLP head at prompt positions only
// ---------------------------------------------------------------------------
__global__ __launch_bounds__(256) void k_mlp(const float* __restrict__ h1,
                                             const float* __restrict__ W1,
                                             const float* __restrict__ b1,
                                             const float* __restrict__ W2,
                                             const float* __restrict__ b2,
                                             const float* __restrict__ pemb,
                                             const int* __restrict__ pidx,
                                             float* __restrict__ out) {
    int blk = blockIdx.x;
    int b = blk >> 4, p = blk & 15;
    int s = pidx[b * NP + p];
    __shared__ float hrow[NH];
    __shared__ float mid[NH];
    int tid = threadIdx.x;
    ((float4*)hrow)[tid] = ((const float4*)(h1 + (size_t)(b * NS + s) * NH))[tid];
    __syncthreads();
    #pragma unroll
    for (int u = 0; u < 4; ++u) {
        int j = tid + 256 * u;
        const float4* wr = (const float4*)(W1 + (size_t)j * NH);
        const float4* hr = (const float4*)hrow;
        float acc = b1[j];
        for (int k = 0; k < NH / 4; ++k) {
            float4 w = wr[k], x = hr[k];
            acc += w.x * x.x + w.y * x.y + w.z * x.z + w.w * x.w;
        }
        mid[j] = fmaxf(acc, 0.f);
    }
    __syncthreads();
    #pragma unroll
    for (int u = 0; u < 4; ++u) {
        int j = tid + 256 * u;
        const float4* wr = (const float4*)(W2 + (size_t)j * NH);
        const float4* mr = (const float4*)mid;
        float acc = b2[j];
        for (int k = 0; k < NH / 4; ++k) {
            float4 w = wr[k], x = mr[k];
            acc += w.x * x.x + w.y * x.y + w.z * x.z + w.w * x.w;
        }
        out[(size_t)(b * NS + s) * NE + j] = acc + pemb[(size_t)p * NE + j];
    }
}

// ---------------------------------------------------------------------------
extern "C" void kernel_launch(void* const* d_in, const int* in_sizes, int n_in,
                              void* d_out, int out_size, void* d_ws, size_t ws_size,
                              hipStream_t stream) {
    const float* emb  = (const float*)d_in[0];
    const float* ctx  = (const float*)d_in[1];
    const float* pemb = (const float*)d_in[2];
    const float* Wih0 = (const float*)d_in[3];
    const float* Whh0 = (const float*)d_in[4];
    const float* bih0 = (const float*)d_in[5];
    const float* bhh0 = (const float*)d_in[6];
    const float* Wih1 = (const float*)d_in[7];
    const float* Whh1 = (const float*)d_in[8];
    const float* bih1 = (const float*)d_in[9];
    const float* bhh1 = (const float*)d_in[10];
    const float* W1   = (const float*)d_in[11];
    const float* b1   = (const float*)d_in[12];
    const float* W2   = (const float*)d_in[13];
    const float* b2   = (const float*)d_in[14];
    const int* ids    = (const int*)d_in[15];
    const int* pidx   = (const int*)d_in[16];
    float* out = (float*)d_out;

    // Workspace layout:
    //   G:    [2][8192][2048] fp32 = 134217728 B
    //   hbuf: [8192][1024]    fp32 =  33554432 B
    //   ctr:  4 ints (barrier counters: layer0 d0/d1, layer1 d0/d1)
    char* ws = (char*)d_ws;
    float* G    = (float*)ws;
    float* hbuf = (float*)(ws + 134217728u);
    int*   ctr  = (int*)(ws + 134217728u + 33554432u);

    float* allb = out;   // reuse d_out as layer-0 input buffer

    k_zero<<<dim3(1), dim3(4), 0, stream>>>(ctr);
    k_allb<<<dim3(NBS), dim3(256), 0, stream>>>(emb, ctx, pemb, ids, pidx, allb);

    // Layer 0: input projections + persistent recurrence
    for (int d = 0; d < 2; ++d)
        k_gemm<<<dim3(NG / 64, NBS / 64), dim3(256), 0, stream>>>(
            allb, Wih0 + (size_t)d * NG * GK, bih0 + d * NG, bhh0 + d * NG,
            G + (size_t)d * NBS * NG);
    k_lstm_p<<<dim3(2 * NWGD), dim3(256), 0, stream>>>(G, Whh0, hbuf, ctr);

    // allb no longer needed: restore raw embeddings into d_out
    k_raw<<<dim3(NBS), dim3(256), 0, stream>>>(emb, ids, out);

    // Layer 1
    for (int d = 0; d < 2; ++d)
        k_gemm<<<dim3(NG / 64, NBS / 64), dim3(256), 0, stream>>>(
            hbuf, Wih1 + (size_t)d * NG * GK, bih1 + d * NG, bhh1 + d * NG,
            G + (size_t)d * NBS * NG);
    k_lstm_p<<<dim3(2 * NWGD), dim3(256), 0, stream>>>(G, Whh1, hbuf, ctr + 2);

    // MLP head at prompt rows only
    k_mlp<<<dim3(NB * NP), dim3(256), 0, stream>>>(hbuf, W1, b1, W2, b2, pemb, pidx, out);
}

// Round 3
// 9294.006 us; speedup vs baseline: 4.2429x; 2.2884x over previous
//
#include <hip/hip_runtime.h>
#include <hip/hip_bf16.h>
#include <math.h>

// Problem constants
constexpr int NB  = 32;      // batch
constexpr int NS  = 256;     // seq len
constexpr int NE  = 1024;    // embed dim
constexpr int NH  = 1024;    // LSTM output dim (2*NHD)
constexpr int NHD = 512;     // per-direction hidden
constexpr int NG  = 2048;    // 4*NHD gates
constexpr int NP  = 16;      // prompt positions
constexpr int NBS = NB * NS; // 8192 rows
constexpr int GK  = 1024;    // GEMM K (= NE = NH)

// Persistent LSTM decomposition
constexpr int UPW  = 8;          // hidden units per WG
constexpr int NWGD = NHD / UPW;  // 64 WGs per direction
constexpr int NSL  = 16;         // K slices (lanes tid&15)
constexpr int KSL  = NHD / NSL;  // 32 floats of K per thread
constexpr int PSTR = 4 * UPW * NB + 4; // partial slice stride (1028 floats)

__device__ __forceinline__ float sigm(float x) { return 1.0f / (1.0f + __expf(-x)); }

// ---------------------------------------------------------------------------
__global__ void k_zero(int* p) { p[threadIdx.x] = 0; }

// ---------------------------------------------------------------------------
// allb[b,s,:] = emb[id]+ctx[id], overwritten by prompt_emb at prompt slots
// ---------------------------------------------------------------------------
__global__ void k_allb(const float* __restrict__ emb, const float* __restrict__ ctx,
                       const float* __restrict__ pemb, const int* __restrict__ ids,
                       const int* __restrict__ pidx, float* __restrict__ allb) {
    int r = blockIdx.x;            // row = b*NS + s
    int b = r >> 8, s = r & 255;
    __shared__ int ppos;
    if (threadIdx.x == 0) {
        int t = -1;
        #pragma unroll
        for (int p = 0; p < NP; ++p)
            if (pidx[b * NP + p] == s) t = p;
        ppos = t;
    }
    __syncthreads();
    int e = threadIdx.x;
    float4 v;
    if (ppos >= 0) {
        v = ((const float4*)(pemb + (size_t)ppos * NE))[e];
    } else {
        int id = ids[r];
        float4 a = ((const float4*)(emb + (size_t)id * NE))[e];
        float4 c = ((const float4*)(ctx + (size_t)id * NE))[e];
        v = make_float4(a.x + c.x, a.y + c.y, a.z + c.z, a.w + c.w);
    }
    ((float4*)(allb + (size_t)r * NE))[e] = v;
}

// ---------------------------------------------------------------------------
__global__ void k_raw(const float* __restrict__ emb, const int* __restrict__ ids,
                      float* __restrict__ out) {
    int r = blockIdx.x;
    int id = ids[r];
    ((float4*)(out + (size_t)r * NE))[threadIdx.x] =
        ((const float4*)(emb + (size_t)id * NE))[threadIdx.x];
}

// ---------------------------------------------------------------------------
// C[8192,2048] = A[8192,1024] @ W[2048,1024]^T + (bih+bhh); A row-major
// ---------------------------------------------------------------------------
__global__ __launch_bounds__(256) void k_gemm(const float* __restrict__ A,
                                              const float* __restrict__ W,
                                              const float* __restrict__ bih,
                                              const float* __restrict__ bhh,
                                              float* __restrict__ C) {
    __shared__ float As[16][65];
    __shared__ float Ws[16][65];
    int tid = threadIdx.x;
    int tx = tid & 15, ty = tid >> 4;
    int n0 = blockIdx.x * 64, m0 = blockIdx.y * 64;
    int lr = tid >> 2;
    int lk = (tid & 3) * 4;
    float acc[4][4] = {};
    for (int kt = 0; kt < GK; kt += 16) {
        float4 av = *(const float4*)(A + (size_t)(m0 + lr) * GK + kt + lk);
        float4 wv = *(const float4*)(W + (size_t)(n0 + lr) * GK + kt + lk);
        As[lk + 0][lr] = av.x; As[lk + 1][lr] = av.y;
        As[lk + 2][lr] = av.z; As[lk + 3][lr] = av.w;
        Ws[lk + 0][lr] = wv.x; Ws[lk + 1][lr] = wv.y;
        Ws[lk + 2][lr] = wv.z; Ws[lk + 3][lr] = wv.w;
        __syncthreads();
        #pragma unroll
        for (int kk = 0; kk < 16; ++kk) {
            float a[4], w[4];
            #pragma unroll
            for (int i = 0; i < 4; ++i) a[i] = As[kk][ty * 4 + i];
            #pragma unroll
            for (int j = 0; j < 4; ++j) w[j] = Ws[kk][tx * 4 + j];
            #pragma unroll
            for (int i = 0; i < 4; ++i)
                #pragma unroll
                for (int j = 0; j < 4; ++j) acc[i][j] += a[i] * w[j];
        }
        __syncthreads();
    }
    #pragma unroll
    for (int j = 0; j < 4; ++j) {
        int n = n0 + tx * 4 + j;
        float bias = bih[n] + bhh[n];
        #pragma unroll
        for (int i = 0; i < 4; ++i)
            C[(size_t)(m0 + ty * 4 + i) * NG + n] = acc[i][j] + bias;
    }
}

// ---------------------------------------------------------------------------
// Same GEMM but A(m,k) comes from hx layout [d][t][b][512]:
//   m = b*256+s (row), k: d = k>=512, col k&511
// ---------------------------------------------------------------------------
__global__ __launch_bounds__(256) void k_gemm2(const float* __restrict__ hx,
                                               const float* __restrict__ W,
                                               const float* __restrict__ bih,
                                               const float* __restrict__ bhh,
                                               float* __restrict__ C) {
    __shared__ float As[16][65];
    __shared__ float Ws[16][65];
    int tid = threadIdx.x;
    int tx = tid & 15, ty = tid >> 4;
    int n0 = blockIdx.x * 64, m0 = blockIdx.y * 64;
    int lr = tid >> 2;
    int lk = (tid & 3) * 4;
    int m = m0 + lr;
    int b = m >> 8, s = m & 255;
    const float* arow0 = hx + ((size_t)s * NB + b) * NHD;                 // dir 0
    const float* arow1 = hx + (((size_t)NS + s) * NB + b) * NHD - NHD;    // dir 1 (base-512)
    float acc[4][4] = {};
    for (int kt = 0; kt < GK; kt += 16) {
        int k = kt + lk;
        const float* abase = (k < NHD) ? arow0 : arow1;
        float4 av = *(const float4*)(abase + k);
        float4 wv = *(const float4*)(W + (size_t)(n0 + lr) * GK + k);
        As[lk + 0][lr] = av.x; As[lk + 1][lr] = av.y;
        As[lk + 2][lr] = av.z; As[lk + 3][lr] = av.w;
        Ws[lk + 0][lr] = wv.x; Ws[lk + 1][lr] = wv.y;
        Ws[lk + 2][lr] = wv.z; Ws[lk + 3][lr] = wv.w;
        __syncthreads();
        #pragma unroll
        for (int kk = 0; kk < 16; ++kk) {
            float a[4], w[4];
            #pragma unroll
            for (int i = 0; i < 4; ++i) a[i] = As[kk][ty * 4 + i];
            #pragma unroll
            for (int j = 0; j < 4; ++j) w[j] = Ws[kk][tx * 4 + j];
            #pragma unroll
            for (int i = 0; i < 4; ++i)
                #pragma unroll
                for (int j = 0; j < 4; ++j) acc[i][j] += a[i] * w[j];
        }
        __syncthreads();
    }
    #pragma unroll
    for (int j = 0; j < 4; ++j) {
        int n = n0 + tx * 4 + j;
        float bias = bih[n] + bhh[n];
        #pragma unroll
        for (int i = 0; i < 4; ++i)
            C[(size_t)(m0 + ty * 4 + i) * NG + n] = acc[i][j] + bias;
    }
}

// ---------------------------------------------------------------------------
// Persistent barrier-synced LSTM recurrence (fence-free LLC exchange).
// Grid = 128 WGs: wg&1 = direction, wg>>1 = 8-unit slice.
// h exchange buffer hx[d][t][b][512]: written with relaxed agent-scope
// (sc1, write-through to LLC) atomic stores; read with PLAIN cached loads
// (step-indexed region is first-touch per XCD L2 -> coherent; 16 WGs/XCD
// share the LLC fetch through their common L2). Barrier = relaxed
// fetch_add + relaxed spin (no cache maintenance anywhere in the loop).
// LDS swizzle: logical float4-col c=8s+m stored at p4=8s+((m+s)&7) ->
// bank-slot (m+s)&7 spreads 16 lanes 2/slot (2-way b128 = free).
// ---------------------------------------------------------------------------
__global__ __launch_bounds__(256) void k_lstm_p(const float* __restrict__ G,
                                                const float* __restrict__ Whh,
                                                float* __restrict__ hx,
                                                int* __restrict__ ctr) {
    __shared__ float h_lds[NB * NHD];      // 64 KB, swizzled
    __shared__ float part[NSL * PSTR];     // 64.25 KB partial sums
    int wg = blockIdx.x;
    int d = wg & 1;
    int slice = wg >> 1;
    int n0 = slice * UPW;
    int tid = threadIdx.x;
    int s  = tid & 15;        // K slice
    int rg = tid >> 4;        // row group 0..15
    int uB = tid >> 5;        // phase-B unit 0..7
    int bB = tid & 31;        // phase-B batch
    int* ctrd = ctr + d;
    float* hxd = hx + (size_t)d * NS * NB * NHD;

    // Resident weights (Whh layout [2][2048][512], gate-major rows)
    float w0[KSL], w1[KSL];
    {
        int r32 = 2 * rg;
        int g0 = r32 >> 3, u0 = r32 & 7;
        int g1 = (r32 + 1) >> 3, u1 = (r32 + 1) & 7;
        const float* p0 = Whh + ((size_t)d * NG + g0 * NHD + n0 + u0) * NHD + s * KSL;
        const float* p1 = Whh + ((size_t)d * NG + g1 * NHD + n0 + u1) * NHD + s * KSL;
        #pragma unroll
        for (int m = 0; m < KSL / 4; ++m) {
            float4 a = ((const float4*)p0)[m];
            w0[4*m] = a.x; w0[4*m+1] = a.y; w0[4*m+2] = a.z; w0[4*m+3] = a.w;
            float4 b = ((const float4*)p1)[m];
            w1[4*m] = b.x; w1[4*m+1] = b.y; w1[4*m+2] = b.z; w1[4*m+3] = b.w;
        }
    }
    float creg = 0.f;
    const float* Gd = G + (size_t)d * NBS * NG;

    for (int step = 0; step < NS; ++step) {
        int tt = d ? (NS - 1 - step) : step;
        // Prefetch this step's input-projection gate values (latency cover)
        float Gv0, Gv1, Gv2, Gv3;
        {
            const float* gp = Gd + (size_t)(bB * NS + tt) * NG + n0 + uB;
            Gv0 = gp[0]; Gv1 = gp[NHD]; Gv2 = gp[2 * NHD]; Gv3 = gp[3 * NHD];
        }
        if (step) {
            // Stage previous h[32][512] into swizzled LDS (plain cached loads)
            int tprev = d ? (NS - step) : (step - 1);
            int r = tid & 7, bRow = tid >> 3;
            const float4* srow = (const float4*)(hxd + ((size_t)tprev * NB + bRow) * NHD);
            float4* drow = (float4*)(h_lds + bRow * NHD);
            #pragma unroll
            for (int i = 0; i < 16; ++i) {
                float4 v = srow[8 * i + r];
                drow[8 * i + ((r + i) & 7)] = v;
            }
            __syncthreads();
            // Phase A: partial dot products, 4 batches at a time
            for (int bb = 0; bb < NB; bb += 4) {
                float a00 = 0, a01 = 0, a02 = 0, a03 = 0;
                float a10 = 0, a11 = 0, a12 = 0, a13 = 0;
                const float4* hb0 = (const float4*)(h_lds + (bb + 0) * NHD);
                const float4* hb1 = (const float4*)(h_lds + (bb + 1) * NHD);
                const float4* hb2 = (const float4*)(h_lds + (bb + 2) * NHD);
                const float4* hb3 = (const float4*)(h_lds + (bb + 3) * NHD);
                #pragma unroll
                for (int m = 0; m < 8; ++m) {
                    int p4 = 8 * s + ((m + s) & 7);
                    float4 h0v = hb0[p4];
                    float4 h1v = hb1[p4];
                    float4 h2v = hb2[p4];
                    float4 h3v = hb3[p4];
#define FMA_B(hv, A0, A1) \
    A0 += w0[4*m]*hv.x + w0[4*m+1]*hv.y + w0[4*m+2]*hv.z + w0[4*m+3]*hv.w; \
    A1 += w1[4*m]*hv.x + w1[4*m+1]*hv.y + w1[4*m+2]*hv.z + w1[4*m+3]*hv.w;
                    FMA_B(h0v, a00, a10)
                    FMA_B(h1v, a01, a11)
                    FMA_B(h2v, a02, a12)
                    FMA_B(h3v, a03, a13)
#undef FMA_B
                }
                int r32 = 2 * rg;
                *(float4*)(part + s * PSTR + r32 * NB + bb)       = make_float4(a00, a01, a02, a03);
                *(float4*)(part + s * PSTR + (r32 + 1) * NB + bb) = make_float4(a10, a11, a12, a13);
            }
        }
        __syncthreads();
        // Phase B: reduce 16 slices, add G row, gate nonlinearity
        float g0 = Gv0, g1 = Gv1, g2 = Gv2, g3 = Gv3;
        if (step) {
            #pragma unroll
            for (int ss = 0; ss < NSL; ++ss) {
                const float* pp = part + ss * PSTR + bB;
                g0 += pp[(0 * UPW + uB) * NB];
                g1 += pp[(1 * UPW + uB) * NB];
                g2 += pp[(2 * UPW + uB) * NB];
                g3 += pp[(3 * UPW + uB) * NB];
            }
        }
        float ig = sigm(g0), fg = sigm(g1), gg = tanhf(g2), og = sigm(g3);
        creg = fg * creg + ig * gg;
        float hv = og * tanhf(creg);
        // Write-through to LLC (sc1, no L2 dirtying, no fences)
        __hip_atomic_store(hxd + ((size_t)tt * NB + bB) * NHD + n0 + uB, hv,
                           __ATOMIC_RELAXED, __HIP_MEMORY_SCOPE_AGENT);
        asm volatile("s_waitcnt vmcnt(0)" ::: "memory");
        __syncthreads();
        if (tid == 0) {
            __hip_atomic_fetch_add(ctrd, 1, __ATOMIC_RELAXED, __HIP_MEMORY_SCOPE_AGENT);
            int target = NWGD * (step + 1);
            while (__hip_atomic_load(ctrd, __ATOMIC_RELAXED, __HIP_MEMORY_SCOPE_AGENT) < target)
                __builtin_amdgcn_s_sleep(1);
        }
        __syncthreads();
    }
}

// ---------------------------------------------------------------------------
// MLP head at prompt positions only; h read from hx[d][t][b][512]
// ---------------------------------------------------------------------------
__global__ __launch_bounds__(256) void k_mlp(const float* __restrict__ hx,
                                             const float* __restrict__ W1,
                                             const float* __restrict__ b1,
                                             const float* __restrict__ W2,
                                             const float* __restrict__ b2,
                                             const float* __restrict__ pemb,
                                             const int* __restrict__ pidx,
                                             float* __restrict__ out) {
    int blk = blockIdx.x;
    int b = blk >> 4, p = blk & 15;
    int s = pidx[b * NP + p];
    __shared__ float hrow[NH];
    __shared__ float mid[NH];
    int tid = threadIdx.x;
    {
        int dsel = tid >> 7;              // 0: fwd units, 1: bwd units
        int off  = tid & 127;             // float4 within direction
        const float* base = hx + (((size_t)dsel * NS + s) * NB + b) * NHD;
        ((float4*)hrow)[tid] = ((const float4*)base)[off];
    }
    __syncthreads();
    #pragma unroll
    for (int u = 0; u < 4; ++u) {
        int j = tid + 256 * u;
        const float4* wr = (const float4*)(W1 + (size_t)j * NH);
        const float4* hr = (const float4*)hrow;
        float acc = b1[j];
        for (int k = 0; k < NH / 4; ++k) {
            float4 w = wr[k], x = hr[k];
            acc += w.x * x.x + w.y * x.y + w.z * x.z + w.w * x.w;
        }
        mid[j] = fmaxf(acc, 0.f);
    }
    __syncthreads();
    #pragma unroll
    for (int u = 0; u < 4; ++u) {
        int j = tid + 256 * u;
        const float4* wr = (const float4*)(W2 + (size_t)j * NH);
        const float4* mr = (const float4*)mid;
        float acc = b2[j];
        for (int k = 0; k < NH / 4; ++k) {
            float4 w = wr[k], x = mr[k];
            acc += w.x * x.x + w.y * x.y + w.z * x.z + w.w * x.w;
        }
        out[(size_t)(b * NS + s) * NE + j] = acc + pemb[(size_t)p * NE + j];
    }
}

// ---------------------------------------------------------------------------
extern "C" void kernel_launch(void* const* d_in, const int* in_sizes, int n_in,
                              void* d_out, int out_size, void* d_ws, size_t ws_size,
                              hipStream_t stream) {
    const float* emb  = (const float*)d_in[0];
    const float* ctx  = (const float*)d_in[1];
    const float* pemb = (const float*)d_in[2];
    const float* Wih0 = (const float*)d_in[3];
    const float* Whh0 = (const float*)d_in[4];
    const float* bih0 = (const float*)d_in[5];
    const float* bhh0 = (const float*)d_in[6];
    const float* Wih1 = (const float*)d_in[7];
    const float* Whh1 = (const float*)d_in[8];
    const float* bih1 = (const float*)d_in[9];
    const float* bhh1 = (const float*)d_in[10];
    const float* W1   = (const float*)d_in[11];
    const float* b1   = (const float*)d_in[12];
    const float* W2   = (const float*)d_in[13];
    const float* b2   = (const float*)d_in[14];
    const int* ids    = (const int*)d_in[15];
    const int* pidx   = (const int*)d_in[16];
    float* out = (float*)d_out;

    // Workspace layout:
    //   G:   [2][8192][2048] fp32 = 134217728 B
    //   hx:  [2][256][32][512] fp32 = 33554432 B (h exchange, reused by both layers)
    //   ctr: 4 ints
    char* ws = (char*)d_ws;
    float* G   = (float*)ws;
    float* hx  = (float*)(ws + 134217728u);
    int*   ctr = (int*)(ws + 134217728u + 33554432u);

    float* allb = out;   // reuse d_out as layer-0 input buffer

    k_zero<<<dim3(1), dim3(4), 0, stream>>>(ctr);
    k_allb<<<dim3(NBS), dim3(256), 0, stream>>>(emb, ctx, pemb, ids, pidx, allb);

    // Layer 0: input projections + persistent recurrence
    for (int d = 0; d < 2; ++d)
        k_gemm<<<dim3(NG / 64, NBS / 64), dim3(256), 0, stream>>>(
            allb, Wih0 + (size_t)d * NG * GK, bih0 + d * NG, bhh0 + d * NG,
            G + (size_t)d * NBS * NG);
    k_lstm_p<<<dim3(2 * NWGD), dim3(256), 0, stream>>>(G, Whh0, hx, ctr);

    // allb no longer needed: restore raw embeddings into d_out
    k_raw<<<dim3(NBS), dim3(256), 0, stream>>>(emb, ids, out);

    // Layer 1 (A comes from hx layout)
    for (int d = 0; d < 2; ++d)
        k_gemm2<<<dim3(NG / 64, NBS / 64), dim3(256), 0, stream>>>(
            hx, Wih1 + (size_t)d * NG * GK, bih1 + d * NG, bhh1 + d * NG,
            G + (size_t)d * NBS * NG);
    k_lstm_p<<<dim3(2 * NWGD), dim3(256), 0, stream>>>(G, Whh1, hx, ctr + 2);

    // MLP head at prompt rows only
    k_mlp<<<dim3(NB * NP), dim3(256), 0, stream>>>(hx, W1, b1, W2, b2, pemb, pidx, out);
}

// Round 4
// 6002.794 us; speedup vs baseline: 6.5691x; 1.5483x over previous
//
#include <hip/hip_runtime.h>
#include <hip/hip_bf16.h>
#include <math.h>

// Problem constants
constexpr int NB  = 32;      // batch
constexpr int NS  = 256;     // seq len
constexpr int NE  = 1024;    // embed dim
constexpr int NH  = 1024;    // LSTM output dim (2*NHD)
constexpr int NHD = 512;     // per-direction hidden
constexpr int NG  = 2048;    // 4*NHD gates
constexpr int NP  = 16;      // prompt positions
constexpr int NBS = NB * NS; // 8192 rows
constexpr int GK  = 1024;    // GEMM K (= NE = NH)

// Persistent LSTM decomposition
constexpr int UPW  = 8;          // hidden units per WG
constexpr int NWGD = NHD / UPW;  // 64 WGs per direction

typedef __attribute__((ext_vector_type(8))) short bf16x8;
typedef __attribute__((ext_vector_type(4))) float f32x4;

__device__ __forceinline__ float sigm(float x) { return 1.0f / (1.0f + __expf(-x)); }
__device__ __forceinline__ unsigned short f2bf(float f) {
    union { float f; unsigned u; } v; v.f = f;
    unsigned r = v.u + 0x7FFF + ((v.u >> 16) & 1);   // RNE
    return (unsigned short)(r >> 16);
}

// ---------------------------------------------------------------------------
__global__ void k_zero(int* p) { p[threadIdx.x] = 0; }

// ---------------------------------------------------------------------------
// allb[b,s,:] = emb[id]+ctx[id], overwritten by prompt_emb at prompt slots
// ---------------------------------------------------------------------------
__global__ void k_allb(const float* __restrict__ emb, const float* __restrict__ ctx,
                       const float* __restrict__ pemb, const int* __restrict__ ids,
                       const int* __restrict__ pidx, float* __restrict__ allb) {
    int r = blockIdx.x;            // row = b*NS + s
    int b = r >> 8, s = r & 255;
    __shared__ int ppos;
    if (threadIdx.x == 0) {
        int t = -1;
        #pragma unroll
        for (int p = 0; p < NP; ++p)
            if (pidx[b * NP + p] == s) t = p;
        ppos = t;
    }
    __syncthreads();
    int e = threadIdx.x;
    float4 v;
    if (ppos >= 0) {
        v = ((const float4*)(pemb + (size_t)ppos * NE))[e];
    } else {
        int id = ids[r];
        float4 a = ((const float4*)(emb + (size_t)id * NE))[e];
        float4 c = ((const float4*)(ctx + (size_t)id * NE))[e];
        v = make_float4(a.x + c.x, a.y + c.y, a.z + c.z, a.w + c.w);
    }
    ((float4*)(allb + (size_t)r * NE))[e] = v;
}

// ---------------------------------------------------------------------------
__global__ void k_raw(const float* __restrict__ emb, const int* __restrict__ ids,
                      float* __restrict__ out) {
    int r = blockIdx.x;
    int id = ids[r];
    ((float4*)(out + (size_t)r * NE))[threadIdx.x] =
        ((const float4*)(emb + (size_t)id * NE))[threadIdx.x];
}

// ---------------------------------------------------------------------------
// C[8192,2048] = A[8192,1024] @ W[2048,1024]^T + (bih+bhh); A row-major, fp32
// ---------------------------------------------------------------------------
__global__ __launch_bounds__(256) void k_gemm(const float* __restrict__ A,
                                              const float* __restrict__ W,
                                              const float* __restrict__ bih,
                                              const float* __restrict__ bhh,
                                              float* __restrict__ C) {
    __shared__ float As[16][65];
    __shared__ float Ws[16][65];
    int tid = threadIdx.x;
    int tx = tid & 15, ty = tid >> 4;
    int n0 = blockIdx.x * 64, m0 = blockIdx.y * 64;
    int lr = tid >> 2;
    int lk = (tid & 3) * 4;
    float acc[4][4] = {};
    for (int kt = 0; kt < GK; kt += 16) {
        float4 av = *(const float4*)(A + (size_t)(m0 + lr) * GK + kt + lk);
        float4 wv = *(const float4*)(W + (size_t)(n0 + lr) * GK + kt + lk);
        As[lk + 0][lr] = av.x; As[lk + 1][lr] = av.y;
        As[lk + 2][lr] = av.z; As[lk + 3][lr] = av.w;
        Ws[lk + 0][lr] = wv.x; Ws[lk + 1][lr] = wv.y;
        Ws[lk + 2][lr] = wv.z; Ws[lk + 3][lr] = wv.w;
        __syncthreads();
        #pragma unroll
        for (int kk = 0; kk < 16; ++kk) {
            float a[4], w[4];
            #pragma unroll
            for (int i = 0; i < 4; ++i) a[i] = As[kk][ty * 4 + i];
            #pragma unroll
            for (int j = 0; j < 4; ++j) w[j] = Ws[kk][tx * 4 + j];
            #pragma unroll
            for (int i = 0; i < 4; ++i)
                #pragma unroll
                for (int j = 0; j < 4; ++j) acc[i][j] += a[i] * w[j];
        }
        __syncthreads();
    }
    #pragma unroll
    for (int j = 0; j < 4; ++j) {
        int n = n0 + tx * 4 + j;
        float bias = bih[n] + bhh[n];
        #pragma unroll
        for (int i = 0; i < 4; ++i)
            C[(size_t)(m0 + ty * 4 + i) * NG + n] = acc[i][j] + bias;
    }
}

// ---------------------------------------------------------------------------
// Same GEMM but A(m,k) comes from hx layout [d][t][b][512]:
//   m = b*256+s (row), k: d = k>=512, col k&511
// ---------------------------------------------------------------------------
__global__ __launch_bounds__(256) void k_gemm2(const float* __restrict__ hx,
                                               const float* __restrict__ W,
                                               const float* __restrict__ bih,
                                               const float* __restrict__ bhh,
                                               float* __restrict__ C) {
    __shared__ float As[16][65];
    __shared__ float Ws[16][65];
    int tid = threadIdx.x;
    int tx = tid & 15, ty = tid >> 4;
    int n0 = blockIdx.x * 64, m0 = blockIdx.y * 64;
    int lr = tid >> 2;
    int lk = (tid & 3) * 4;
    int m = m0 + lr;
    int b = m >> 8, s = m & 255;
    const float* arow0 = hx + ((size_t)s * NB + b) * NHD;                 // dir 0
    const float* arow1 = hx + (((size_t)NS + s) * NB + b) * NHD - NHD;    // dir 1 (base-512)
    float acc[4][4] = {};
    for (int kt = 0; kt < GK; kt += 16) {
        int k = kt + lk;
        const float* abase = (k < NHD) ? arow0 : arow1;
        float4 av = *(const float4*)(abase + k);
        float4 wv = *(const float4*)(W + (size_t)(n0 + lr) * GK + k);
        As[lk + 0][lr] = av.x; As[lk + 1][lr] = av.y;
        As[lk + 2][lr] = av.z; As[lk + 3][lr] = av.w;
        Ws[lk + 0][lr] = wv.x; Ws[lk + 1][lr] = wv.y;
        Ws[lk + 2][lr] = wv.z; Ws[lk + 3][lr] = wv.w;
        __syncthreads();
        #pragma unroll
        for (int kk = 0; kk < 16; ++kk) {
            float a[4], w[4];
            #pragma unroll
            for (int i = 0; i < 4; ++i) a[i] = As[kk][ty * 4 + i];
            #pragma unroll
            for (int j = 0; j < 4; ++j) w[j] = Ws[kk][tx * 4 + j];
            #pragma unroll
            for (int i = 0; i < 4; ++i)
                #pragma unroll
                for (int j = 0; j < 4; ++j) acc[i][j] += a[i] * w[j];
        }
        __syncthreads();
    }
    #pragma unroll
    for (int j = 0; j < 4; ++j) {
        int n = n0 + tx * 4 + j;
        float bias = bih[n] + bhh[n];
        #pragma unroll
        for (int i = 0; i < 4; ++i)
            C[(size_t)(m0 + ty * 4 + i) * NG + n] = acc[i][j] + bias;
    }
}

// ---------------------------------------------------------------------------
// MFMA persistent LSTM recurrence.
// Grid = 128 WGs: wg&1 = direction, wg>>1 = 8-unit slice (n0 = slice*8).
// Per step per WG: 32x32x512 matmul -> gates. Local row r = u*4 + g
// (u = unit 0..7, g = gate i,f,g,o). Wave w: ublock = w&1 (units 4*ublock..),
// bblock = w>>1 (batches 16*bblock..). A (weights) resident: 16 bf16x8
// fragments/lane (lane: row = lane&15 -> u=(r>>2), g=(r&3); kblock = lane>>4).
// B (h) from 32KB bf16 LDS tile, XOR-swizzled byte ^= (row&7)<<4.
// C/D (m89): col = lane&15 = batch, row = (lane>>4)*4 + reg -> reg = gate!
// h exchange: fp32 hx[d][t][b][512], sc1 relaxed atomic stores + plain
// cached staging reads + relaxed spin barrier (proven R3 pattern).
// ---------------------------------------------------------------------------
__global__ __launch_bounds__(256) void k_lstm_m(const float* __restrict__ G,
                                                const float* __restrict__ Whh,
                                                float* __restrict__ hx,
                                                int* __restrict__ ctr) {
    __shared__ char hlds[NB * NHD * 2];    // 32 KB bf16, swizzled
    int wg = blockIdx.x;
    int d = wg & 1;
    int slice = wg >> 1;
    int n0 = slice * UPW;
    int tid = threadIdx.x;
    int lane = tid & 63;
    int wv = tid >> 6;
    int ublock = wv & 1, bblock = wv >> 1;
    int* ctrd = ctr + d;
    float* hxd = hx + (size_t)d * NS * NB * NHD;
    const float* Gd = G + (size_t)d * NBS * NG;

    // ---- resident A fragments (weights -> bf16) ----
    bf16x8 wfrag[16];
    {
        int rloc = lane & 15;
        int usub = rloc >> 2, g = rloc & 3;
        int kb = lane >> 4;
        const float* wrow = Whh + ((size_t)d * NG + g * NHD + n0 + ublock * 4 + usub) * NHD;
        #pragma unroll
        for (int kk = 0; kk < 16; ++kk) {
            const float* p = wrow + kk * 32 + kb * 8;
            float4 x = *(const float4*)p;
            float4 y = *(const float4*)(p + 4);
            bf16x8 w;
            w[0] = (short)f2bf(x.x); w[1] = (short)f2bf(x.y);
            w[2] = (short)f2bf(x.z); w[3] = (short)f2bf(x.w);
            w[4] = (short)f2bf(y.x); w[5] = (short)f2bf(y.y);
            w[6] = (short)f2bf(y.z); w[7] = (short)f2bf(y.w);
            wfrag[kk] = w;
        }
    }
    int usub_c = lane >> 4;                 // C-layout unit-sub (= kb)
    int bcol   = bblock * 16 + (lane & 15); // batch (B & C cols)
    int unitC  = n0 + ublock * 4 + usub_c;  // global unit of this lane's gates
    int kb     = lane >> 4;                 // B k-block
    int c8 = tid & 7, bRow = tid >> 3;      // staging role

    float creg = 0.f;
    for (int step = 0; step < NS; ++step) {
        int tt = d ? (NS - 1 - step) : step;
        // G prefetch (4 gate pre-activations for this lane's (unit,batch))
        const float* gp = Gd + ((size_t)bcol * NS + tt) * NG + unitC;
        float Gv0 = gp[0], Gv1 = gp[NHD], Gv2 = gp[2 * NHD], Gv3 = gp[3 * NHD];
        f32x4 acc = {0.f, 0.f, 0.f, 0.f};
        if (step) {
            int tprev = d ? tt + 1 : tt - 1;
            // stage hx[tprev][32][512] -> bf16 swizzled LDS (thread: row bRow,
            // 64-float chunk c8)
            const float4* srow =
                (const float4*)(hxd + ((size_t)tprev * NB + bRow) * NHD + c8 * 64);
            char* dstrow = hlds + bRow * 1024;
            unsigned rsw = (unsigned)((bRow & 7) << 4);
            #pragma unroll
            for (int i = 0; i < 8; ++i) {
                float4 a = srow[2 * i], b = srow[2 * i + 1];
                uint4 cv;
                cv.x = (unsigned)f2bf(a.x) | ((unsigned)f2bf(a.y) << 16);
                cv.y = (unsigned)f2bf(a.z) | ((unsigned)f2bf(a.w) << 16);
                cv.z = (unsigned)f2bf(b.x) | ((unsigned)f2bf(b.y) << 16);
                cv.w = (unsigned)f2bf(b.z) | ((unsigned)f2bf(b.w) << 16);
                *(uint4*)(dstrow + (((unsigned)(c8 * 128 + i * 16)) ^ rsw)) = cv;
            }
            __syncthreads();
            // 16 K-steps: ds_read B-frag + MFMA
            const char* bbase = hlds + bcol * 1024;
            unsigned bsw = (unsigned)((bcol & 7) << 4);
            #pragma unroll
            for (int kk = 0; kk < 16; ++kk) {
                bf16x8 bf = *(const bf16x8*)(bbase + (((unsigned)(kk * 64 + kb * 16)) ^ bsw));
                acc = __builtin_amdgcn_mfma_f32_16x16x32_bf16(wfrag[kk], bf, acc, 0, 0, 0);
            }
            __syncthreads();   // LDS reads done before next step's staging writes
        }
        // gates: reg q = gate q (i,f,g,o) for (unitC, bcol)
        float ig = sigm(acc[0] + Gv0);
        float fg = sigm(acc[1] + Gv1);
        float gg = tanhf(acc[2] + Gv2);
        float og = sigm(acc[3] + Gv3);
        creg = fg * creg + ig * gg;
        float hv = og * tanhf(creg);
        // write-through to LLC (sc1, relaxed)
        __hip_atomic_store(hxd + ((size_t)tt * NB + bcol) * NHD + unitC, hv,
                           __ATOMIC_RELAXED, __HIP_MEMORY_SCOPE_AGENT);
        asm volatile("s_waitcnt vmcnt(0)" ::: "memory");
        __syncthreads();
        if (tid == 0) {
            __hip_atomic_fetch_add(ctrd, 1, __ATOMIC_RELAXED, __HIP_MEMORY_SCOPE_AGENT);
            int target = NWGD * (step + 1);
            while (__hip_atomic_load(ctrd, __ATOMIC_RELAXED, __HIP_MEMORY_SCOPE_AGENT) < target)
                __builtin_amdgcn_s_sleep(1);
        }
        __syncthreads();
    }
}

// ---------------------------------------------------------------------------
// MLP head at prompt positions only; h read from hx[d][t][b][512]
// ---------------------------------------------------------------------------
__global__ __launch_bounds__(256) void k_mlp(const float* __restrict__ hx,
                                             const float* __restrict__ W1,
                                             const float* __restrict__ b1,
                                             const float* __restrict__ W2,
                                             const float* __restrict__ b2,
                                             const float* __restrict__ pemb,
                                             const int* __restrict__ pidx,
                                             float* __restrict__ out) {
    int blk = blockIdx.x;
    int b = blk >> 4, p = blk & 15;
    int s = pidx[b * NP + p];
    __shared__ float hrow[NH];
    __shared__ float mid[NH];
    int tid = threadIdx.x;
    {
        int dsel = tid >> 7;              // 0: fwd units, 1: bwd units
        int off  = tid & 127;             // float4 within direction
        const float* base = hx + (((size_t)dsel * NS + s) * NB + b) * NHD;
        ((float4*)hrow)[tid] = ((const float4*)base)[off];
    }
    __syncthreads();
    #pragma unroll
    for (int u = 0; u < 4; ++u) {
        int j = tid + 256 * u;
        const float4* wr = (const float4*)(W1 + (size_t)j * NH);
        const float4* hr = (const float4*)hrow;
        float acc = b1[j];
        for (int k = 0; k < NH / 4; ++k) {
            float4 w = wr[k], x = hr[k];
            acc += w.x * x.x + w.y * x.y + w.z * x.z + w.w * x.w;
        }
        mid[j] = fmaxf(acc, 0.f);
    }
    __syncthreads();
    #pragma unroll
    for (int u = 0; u < 4; ++u) {
        int j = tid + 256 * u;
        const float4* wr = (const float4*)(W2 + (size_t)j * NH);
        const float4* mr = (const float4*)mid;
        float acc = b2[j];
        for (int k = 0; k < NH / 4; ++k) {
            float4 w = wr[k], x = mr[k];
            acc += w.x * x.x + w.y * x.y + w.z * x.z + w.w * x.w;
        }
        out[(size_t)(b * NS + s) * NE + j] = acc + pemb[(size_t)p * NE + j];
    }
}

// ---------------------------------------------------------------------------
extern "C" void kernel_launch(void* const* d_in, const int* in_sizes, int n_in,
                              void* d_out, int out_size, void* d_ws, size_t ws_size,
                              hipStream_t stream) {
    const float* emb  = (const float*)d_in[0];
    const float* ctx  = (const float*)d_in[1];
    const float* pemb = (const float*)d_in[2];
    const float* Wih0 = (const float*)d_in[3];
    const float* Whh0 = (const float*)d_in[4];
    const float* bih0 = (const float*)d_in[5];
    const float* bhh0 = (const float*)d_in[6];
    const float* Wih1 = (const float*)d_in[7];
    const float* Whh1 = (const float*)d_in[8];
    const float* bih1 = (const float*)d_in[9];
    const float* bhh1 = (const float*)d_in[10];
    const float* W1   = (const float*)d_in[11];
    const float* b1   = (const float*)d_in[12];
    const float* W2   = (const float*)d_in[13];
    const float* b2   = (const float*)d_in[14];
    const int* ids    = (const int*)d_in[15];
    const int* pidx   = (const int*)d_in[16];
    float* out = (float*)d_out;

    // Workspace layout:
    //   G:   [2][8192][2048] fp32 = 134217728 B
    //   hx:  [2][256][32][512] fp32 = 33554432 B (h exchange, both layers)
    //   ctr: 4 ints
    char* ws = (char*)d_ws;
    float* G   = (float*)ws;
    float* hx  = (float*)(ws + 134217728u);
    int*   ctr = (int*)(ws + 134217728u + 33554432u);

    float* allb = out;   // reuse d_out as layer-0 input buffer

    k_zero<<<dim3(1), dim3(4), 0, stream>>>(ctr);
    k_allb<<<dim3(NBS), dim3(256), 0, stream>>>(emb, ctx, pemb, ids, pidx, allb);

    // Layer 0: input projections + persistent MFMA recurrence
    for (int d = 0; d < 2; ++d)
        k_gemm<<<dim3(NG / 64, NBS / 64), dim3(256), 0, stream>>>(
            allb, Wih0 + (size_t)d * NG * GK, bih0 + d * NG, bhh0 + d * NG,
            G + (size_t)d * NBS * NG);
    k_lstm_m<<<dim3(2 * NWGD), dim3(256), 0, stream>>>(G, Whh0, hx, ctr);

    // allb no longer needed: restore raw embeddings into d_out
    k_raw<<<dim3(NBS), dim3(256), 0, stream>>>(emb, ids, out);

    // Layer 1 (A comes from hx layout)
    for (int d = 0; d < 2; ++d)
        k_gemm2<<<dim3(NG / 64, NBS / 64), dim3(256), 0, stream>>>(
            hx, Wih1 + (size_t)d * NG * GK, bih1 + d * NG, bhh1 + d * NG,
            G + (size_t)d * NBS * NG);
    k_lstm_m<<<dim3(2 * NWGD), dim3(256), 0, stream>>>(G, Whh1, hx, ctr + 2);

    // MLP head at prompt rows only
    k_mlp<<<dim3(NB * NP), dim3(256), 0, stream>>>(hx, W1, b1, W2, b2, pemb, pidx, out);
}

// Round 5
// 2557.339 us; speedup vs baseline: 15.4196x; 2.3473x over previous
//
#include <hip/hip_runtime.h>
#include <hip/hip_bf16.h>
#include <math.h>

// Problem constants
constexpr int NB  = 32;      // batch
constexpr int NS  = 256;     // seq len
constexpr int NE  = 1024;    // embed dim
constexpr int NH  = 1024;    // LSTM output dim (2*NHD)
constexpr int NHD = 512;     // per-direction hidden
constexpr int NG  = 2048;    // 4*NHD gates
constexpr int NP  = 16;      // prompt positions
constexpr int NBS = NB * NS; // 8192 rows
constexpr int GK  = 1024;    // GEMM K (= NE = NH)

// Persistent LSTM decomposition
constexpr int UPW  = 8;          // hidden units per WG
constexpr int NWGD = NHD / UPW;  // 64 WGs per direction

// Gt layout: [d][slice 64][t 256][b 32][unitLoc 8][gate 4] fp32
constexpr size_t GT_DIR = (size_t)64 * 256 * 1024;  // elems per direction

typedef __attribute__((ext_vector_type(8))) short bf16x8;
typedef __attribute__((ext_vector_type(4))) float f32x4;
typedef unsigned short u16;

__device__ __forceinline__ float sigm(float x) { return 1.0f / (1.0f + __expf(-x)); }
__device__ __forceinline__ u16 f2bf(float f) {
    union { float f; unsigned u; } v; v.f = f;
    unsigned r = v.u + 0x7FFF + ((v.u >> 16) & 1);   // RNE
    return (u16)(r >> 16);
}
__device__ __forceinline__ float bf2f(u16 b) {
    return __uint_as_float((unsigned)b << 16);
}

// ---------------------------------------------------------------------------
__global__ void k_zero(int* p) { p[threadIdx.x] = 0; }

// ---------------------------------------------------------------------------
// allb_bf[s][b][1024] (bf16) = emb[id]+ctx[id], prompt_emb at prompt slots
// ---------------------------------------------------------------------------
__global__ void k_allb(const float* __restrict__ emb, const float* __restrict__ ctx,
                       const float* __restrict__ pemb, const int* __restrict__ ids,
                       const int* __restrict__ pidx, u16* __restrict__ allb) {
    int r = blockIdx.x;            // r = b*NS + s
    int b = r >> 8, s = r & 255;
    __shared__ int ppos;
    if (threadIdx.x == 0) {
        int t = -1;
        #pragma unroll
        for (int p = 0; p < NP; ++p)
            if (pidx[b * NP + p] == s) t = p;
        ppos = t;
    }
    __syncthreads();
    int e = threadIdx.x;
    float4 v;
    if (ppos >= 0) {
        v = ((const float4*)(pemb + (size_t)ppos * NE))[e];
    } else {
        int id = ids[r];
        float4 a = ((const float4*)(emb + (size_t)id * NE))[e];
        float4 c = ((const float4*)(ctx + (size_t)id * NE))[e];
        v = make_float4(a.x + c.x, a.y + c.y, a.z + c.z, a.w + c.w);
    }
    ushort4 o;
    o.x = f2bf(v.x); o.y = f2bf(v.y); o.z = f2bf(v.z); o.w = f2bf(v.w);
    *(ushort4*)(allb + ((size_t)(s * NB + b)) * NE + e * 4) = o;
}

// ---------------------------------------------------------------------------
__global__ void k_raw(const float* __restrict__ emb, const int* __restrict__ ids,
                      float* __restrict__ out) {
    int r = blockIdx.x;
    int id = ids[r];
    ((float4*)(out + (size_t)r * NE))[threadIdx.x] =
        ((const float4*)(emb + (size_t)id * NE))[threadIdx.x];
}

// ---------------------------------------------------------------------------
// Wih ([2][2048][1024] fp32, gate-major rows) -> Wbf ([2][2048][1024] bf16,
// UNIT-MAJOR rows: n' = unit*4+gate) + combined bias in same order.
// ---------------------------------------------------------------------------
__global__ void k_wcvt(const float* __restrict__ Wih, const float* __restrict__ bih,
                       const float* __restrict__ bhh, u16* __restrict__ Wbf,
                       float* __restrict__ biasC) {
    int blk = blockIdx.x;               // [2][2048]
    int d = blk >> 11, np = blk & 2047;
    int rw = (np & 3) * 512 + (np >> 2);
    const float* src = Wih + ((size_t)d * NG + rw) * GK;
    u16* dst = Wbf + ((size_t)d * NG + np) * GK;
    int t = threadIdx.x;
    float4 v = ((const float4*)src)[t];
    ushort4 o;
    o.x = f2bf(v.x); o.y = f2bf(v.y); o.z = f2bf(v.z); o.w = f2bf(v.w);
    ((ushort4*)dst)[t] = o;
    if (t == 0)
        biasC[d * NG + np] = bih[d * NG + rw] + bhh[d * NG + rw];
}

// ---------------------------------------------------------------------------
// bf16 MFMA GEMM: Gt[slice][t][b][u][g] = A[m',k] @ Wbf[n',k]^T + biasC
// m' = t*32+b (8192), n' = unit*4+g (2048 per dir), K = 1024.
// A: bf16, k<512 from A0 + m'*astride + k, else A1 + m'*astride + (k-512).
// 128x128 tile, BK=64, 4 waves, 4x4 16x16x32 frags/wave.
// LDS XOR swizzle: byte = r*128 + (coff ^ ((r&7)<<4)).
// ---------------------------------------------------------------------------
__global__ __launch_bounds__(256) void k_gemm_m(const u16* __restrict__ A0,
                                                const u16* __restrict__ A1,
                                                int astride,
                                                const u16* __restrict__ W,
                                                const float* __restrict__ bc,
                                                float* __restrict__ Gt) {
    __shared__ char At[128 * 128];
    __shared__ char Wt[128 * 128];
    int tid = threadIdx.x;
    int lane = tid & 63, w = tid >> 6;
    int n0 = blockIdx.x * 128, m0 = blockIdx.y * 128;
    int r = tid >> 1, h = tid & 1;      // staging: row r, half h

    f32x4 acc[4][4];
    #pragma unroll
    for (int i = 0; i < 4; ++i)
        #pragma unroll
        for (int j = 0; j < 4; ++j) acc[i][j] = (f32x4){0.f, 0.f, 0.f, 0.f};

    unsigned rsw = (unsigned)((r & 7) << 4);
    for (int kt = 0; kt < GK; kt += 64) {
        // ---- stage A tile (128 rows x 64 bf16) ----
        {
            int k0 = kt + h * 32;
            const u16* asrc = (k0 < 512) ? (A0 + (size_t)(m0 + r) * astride + k0)
                                         : (A1 + (size_t)(m0 + r) * astride + (k0 - 512));
            const u16* wsrc = W + (size_t)(n0 + r) * GK + k0;
            #pragma unroll
            for (int j = 0; j < 4; ++j) {
                uint4 va = *(const uint4*)(asrc + j * 8);
                *(uint4*)(At + r * 128 + (((unsigned)(h * 64 + j * 16)) ^ rsw)) = va;
                uint4 vw = *(const uint4*)(wsrc + j * 8);
                *(uint4*)(Wt + r * 128 + (((unsigned)(h * 64 + j * 16)) ^ rsw)) = vw;
            }
        }
        __syncthreads();
        #pragma unroll
        for (int sub = 0; sub < 2; ++sub) {
            bf16x8 af[4], bfr[4];
            int kbyte = sub * 64 + (lane >> 4) * 16;
            #pragma unroll
            for (int ni = 0; ni < 4; ++ni) {
                int rr = (w & 1) * 64 + ni * 16 + (lane & 15);
                af[ni] = *(const bf16x8*)(Wt + rr * 128 + ((unsigned)kbyte ^ ((unsigned)((rr & 7) << 4))));
            }
            #pragma unroll
            for (int mi = 0; mi < 4; ++mi) {
                int rr = (w >> 1) * 64 + mi * 16 + (lane & 15);
                bfr[mi] = *(const bf16x8*)(At + rr * 128 + ((unsigned)kbyte ^ ((unsigned)((rr & 7) << 4))));
            }
            #pragma unroll
            for (int mi = 0; mi < 4; ++mi)
                #pragma unroll
                for (int ni = 0; ni < 4; ++ni)
                    acc[mi][ni] = __builtin_amdgcn_mfma_f32_16x16x32_bf16(
                        af[ni], bfr[mi], acc[mi][ni], 0, 0, 0);
        }
        __syncthreads();
    }
    // ---- epilogue: float4 (4 gates of one unit) per frag per lane ----
    #pragma unroll
    for (int mi = 0; mi < 4; ++mi) {
        int mp = m0 + (w >> 1) * 64 + mi * 16 + (lane & 15);
        int t = mp >> 5, b = mp & 31;
        #pragma unroll
        for (int ni = 0; ni < 4; ++ni) {
            int npb = n0 + (w & 1) * 64 + ni * 16 + (lane >> 4) * 4;
            int unit = npb >> 2;
            float4 bv = *(const float4*)(bc + npb);
            f32x4 a = acc[mi][ni];
            float4 o = make_float4(a[0] + bv.x, a[1] + bv.y, a[2] + bv.z, a[3] + bv.w);
            *(float4*)(Gt + ((size_t)((unit >> 3) * NS + t)) * 1024 + b * 32 + (unit & 7) * 4) = o;
        }
    }
}

// ---------------------------------------------------------------------------
// MFMA persistent LSTM recurrence (structure proven R4; new G layout + bf16 hx).
// Grid = 128 WGs: wg&1 = dir, wg>>1 = 8-unit slice. Per step: 32x32x512 MFMA.
// G-read: ONE coalesced float4 (4 gates) per lane from Gt.
// hx_bf[d][t][b][512] bf16: producer 1 ushort sc1-relaxed store; staging =
// pure uint4 copies into XOR-swizzled LDS (no cvt). Barrier: relaxed ctr.
// ---------------------------------------------------------------------------
__global__ __launch_bounds__(256) void k_lstm_f(const float* __restrict__ Gt,
                                                const float* __restrict__ Whh,
                                                u16* __restrict__ hxb,
                                                int* __restrict__ ctr) {
    __shared__ char hlds[NB * NHD * 2];    // 32 KB bf16, swizzled
    int wg = blockIdx.x;
    int d = wg & 1;
    int slice = wg >> 1;
    int n0 = slice * UPW;
    int tid = threadIdx.x;
    int lane = tid & 63;
    int wv = tid >> 6;
    int ublock = wv & 1, bblock = wv >> 1;
    int* ctrd = ctr + d;
    u16* hxd = hxb + (size_t)d * NS * NB * NHD;
    const float* Gd = Gt + (size_t)d * GT_DIR + (size_t)slice * NS * 1024;

    // resident A fragments (Whh fp32 -> bf16), mapping verified R4
    bf16x8 wfrag[16];
    {
        int rloc = lane & 15;
        int usub = rloc >> 2, g = rloc & 3;
        int kb = lane >> 4;
        const float* wrow = Whh + ((size_t)d * NG + g * NHD + n0 + ublock * 4 + usub) * NHD;
        #pragma unroll
        for (int kk = 0; kk < 16; ++kk) {
            const float* p = wrow + kk * 32 + kb * 8;
            float4 x = *(const float4*)p;
            float4 y = *(const float4*)(p + 4);
            bf16x8 wf;
            wf[0] = (short)f2bf(x.x); wf[1] = (short)f2bf(x.y);
            wf[2] = (short)f2bf(x.z); wf[3] = (short)f2bf(x.w);
            wf[4] = (short)f2bf(y.x); wf[5] = (short)f2bf(y.y);
            wf[6] = (short)f2bf(y.z); wf[7] = (short)f2bf(y.w);
            wfrag[kk] = wf;
        }
    }
    int usub_c = lane >> 4;                 // C-layout unit-sub
    int bcol   = bblock * 16 + (lane & 15); // batch
    int unitC  = n0 + ublock * 4 + usub_c;  // global unit
    int kb     = lane >> 4;                 // B k-block
    int c8 = tid & 7, bRow = tid >> 3;      // staging role

    float creg = 0.f;
    for (int step = 0; step < NS; ++step) {
        int tt = d ? (NS - 1 - step) : step;
        // coalesced G read: 4 gate pre-activations in one float4
        float4 Gv = *(const float4*)(Gd + (size_t)tt * 1024 + bcol * 32 +
                                     (ublock * 4 + usub_c) * 4);
        f32x4 acc = {0.f, 0.f, 0.f, 0.f};
        if (step) {
            int tprev = d ? tt + 1 : tt - 1;
            // stage hx_bf[tprev] (32KB) -> swizzled LDS, pure copies
            const u16* srow = hxd + ((size_t)tprev * NB + bRow) * NHD;
            char* dstrow = hlds + bRow * 1024;
            unsigned rsw = (unsigned)((bRow & 7) << 4);
            #pragma unroll
            for (int i = 0; i < 8; ++i) {
                uint4 v = *(const uint4*)(srow + c8 * 64 + i * 8);
                *(uint4*)(dstrow + (((unsigned)(c8 * 128 + i * 16)) ^ rsw)) = v;
            }
            __syncthreads();
            const char* bbase = hlds + bcol * 1024;
            unsigned bsw = (unsigned)((bcol & 7) << 4);
            #pragma unroll
            for (int kk = 0; kk < 16; ++kk) {
                bf16x8 bf = *(const bf16x8*)(bbase + (((unsigned)(kk * 64 + kb * 16)) ^ bsw));
                acc = __builtin_amdgcn_mfma_f32_16x16x32_bf16(wfrag[kk], bf, acc, 0, 0, 0);
            }
            __syncthreads();   // LDS reads done before next step's staging
        }
        float ig = sigm(acc[0] + Gv.x);
        float fg = sigm(acc[1] + Gv.y);
        float gg = tanhf(acc[2] + Gv.z);
        float og = sigm(acc[3] + Gv.w);
        creg = fg * creg + ig * gg;
        float hv = og * tanhf(creg);
        // write-through to LLC (sc1, relaxed), bf16
        __hip_atomic_store(hxd + ((size_t)tt * NB + bcol) * NHD + unitC, f2bf(hv),
                           __ATOMIC_RELAXED, __HIP_MEMORY_SCOPE_AGENT);
        asm volatile("s_waitcnt vmcnt(0)" ::: "memory");
        __syncthreads();
        if (tid == 0) {
            __hip_atomic_fetch_add(ctrd, 1, __ATOMIC_RELAXED, __HIP_MEMORY_SCOPE_AGENT);
            int target = NWGD * (step + 1);
            while (__hip_atomic_load(ctrd, __ATOMIC_RELAXED, __HIP_MEMORY_SCOPE_AGENT) < target)
                __builtin_amdgcn_s_sleep(1);
        }
        __syncthreads();
    }
}

// ---------------------------------------------------------------------------
// MLP stage 1: mid[512][1024] = relu(hrow @ W1^T + b1), rows gathered from
// hx_bf at prompt positions. 64x64 fp32 tile (proven R1 structure).
// ---------------------------------------------------------------------------
__global__ __launch_bounds__(256) void k_mlp1(const u16* __restrict__ hxb,
                                              const int* __restrict__ pidx,
                                              const float* __restrict__ W1,
                                              const float* __restrict__ b1,
                                              float* __restrict__ mid) {
    __shared__ float As[16][65];
    __shared__ float Ws[16][65];
    int tid = threadIdx.x;
    int tx = tid & 15, ty = tid >> 4;
    int n0 = blockIdx.x * 64, m0 = blockIdx.y * 64;
    int lr = tid >> 2;
    int lk = (tid & 3) * 4;
    int m = m0 + lr;
    int bb = m >> 4;
    int s = pidx[m];
    float acc[4][4] = {};
    for (int kt = 0; kt < GK; kt += 16) {
        int k0 = kt + lk;
        int half = k0 >> 9;
        ushort4 av4 = *(const ushort4*)(hxb + (((size_t)(half * NS + s)) * NB + bb) * NHD + (k0 & 511));
        float4 wv = *(const float4*)(W1 + (size_t)(n0 + lr) * GK + k0);
        As[lk + 0][lr] = bf2f(av4.x); As[lk + 1][lr] = bf2f(av4.y);
        As[lk + 2][lr] = bf2f(av4.z); As[lk + 3][lr] = bf2f(av4.w);
        Ws[lk + 0][lr] = wv.x; Ws[lk + 1][lr] = wv.y;
        Ws[lk + 2][lr] = wv.z; Ws[lk + 3][lr] = wv.w;
        __syncthreads();
        #pragma unroll
        for (int kk = 0; kk < 16; ++kk) {
            float a[4], w[4];
            #pragma unroll
            for (int i = 0; i < 4; ++i) a[i] = As[kk][ty * 4 + i];
            #pragma unroll
            for (int j = 0; j < 4; ++j) w[j] = Ws[kk][tx * 4 + j];
            #pragma unroll
            for (int i = 0; i < 4; ++i)
                #pragma unroll
                for (int j = 0; j < 4; ++j) acc[i][j] += a[i] * w[j];
        }
        __syncthreads();
    }
    #pragma unroll
    for (int j = 0; j < 4; ++j) {
        int n = n0 + tx * 4 + j;
        float bias = b1[n];
        #pragma unroll
        for (int i = 0; i < 4; ++i)
            mid[(size_t)(m0 + ty * 4 + i) * 1024 + n] = fmaxf(acc[i][j] + bias, 0.f);
    }
}

// ---------------------------------------------------------------------------
// MLP stage 2: out[b, s] = mid @ W2^T + b2 + pemb[p], scattered to d_out.
// ---------------------------------------------------------------------------
__global__ __launch_bounds__(256) void k_mlp2(const float* __restrict__ mid,
                                              const int* __restrict__ pidx,
                                              const float* __restrict__ W2,
                                              const float* __restrict__ b2,
                                              const float* __restrict__ pemb,
                                              float* __restrict__ out) {
    __shared__ float As[16][65];
    __shared__ float Ws[16][65];
    int tid = threadIdx.x;
    int tx = tid & 15, ty = tid >> 4;
    int n0 = blockIdx.x * 64, m0 = blockIdx.y * 64;
    int lr = tid >> 2;
    int lk = (tid & 3) * 4;
    float acc[4][4] = {};
    for (int kt = 0; kt < GK; kt += 16) {
        float4 av = *(const float4*)(mid + (size_t)(m0 + lr) * GK + kt + lk);
        float4 wv = *(const float4*)(W2 + (size_t)(n0 + lr) * GK + kt + lk);
        As[lk + 0][lr] = av.x; As[lk + 1][lr] = av.y;
        As[lk + 2][lr] = av.z; As[lk + 3][lr] = av.w;
        Ws[lk + 0][lr] = wv.x; Ws[lk + 1][lr] = wv.y;
        Ws[lk + 2][lr] = wv.z; Ws[lk + 3][lr] = wv.w;
        __syncthreads();
        #pragma unroll
        for (int kk = 0; kk < 16; ++kk) {
            float a[4], w[4];
            #pragma unroll
            for (int i = 0; i < 4; ++i) a[i] = As[kk][ty * 4 + i];
            #pragma unroll
            for (int j = 0; j < 4; ++j) w[j] = Ws[kk][tx * 4 + j];
            #pragma unroll
            for (int i = 0; i < 4; ++i)
                #pragma unroll
                for (int j = 0; j < 4; ++j) acc[i][j] += a[i] * w[j];
        }
        __syncthreads();
    }
    #pragma unroll
    for (int i = 0; i < 4; ++i) {
        int m = m0 + ty * 4 + i;
        int bb = m >> 4, p = m & 15;
        int s = pidx[m];
        float* orow = out + ((size_t)(bb * NS + s)) * NE;
        const float* prow = pemb + (size_t)p * NE;
        #pragma unroll
        for (int j = 0; j < 4; ++j) {
            int n = n0 + tx * 4 + j;
            orow[n] = acc[i][j] + b2[n] + prow[n];
        }
    }
}

// ---------------------------------------------------------------------------
extern "C" void kernel_launch(void* const* d_in, const int* in_sizes, int n_in,
                              void* d_out, int out_size, void* d_ws, size_t ws_size,
                              hipStream_t stream) {
    const float* emb  = (const float*)d_in[0];
    const float* ctx  = (const float*)d_in[1];
    const float* pemb = (const float*)d_in[2];
    const float* Wih0 = (const float*)d_in[3];
    const float* Whh0 = (const float*)d_in[4];
    const float* bih0 = (const float*)d_in[5];
    const float* bhh0 = (const float*)d_in[6];
    const float* Wih1 = (const float*)d_in[7];
    const float* Whh1 = (const float*)d_in[8];
    const float* bih1 = (const float*)d_in[9];
    const float* bhh1 = (const float*)d_in[10];
    const float* W1   = (const float*)d_in[11];
    const float* b1   = (const float*)d_in[12];
    const float* W2   = (const float*)d_in[13];
    const float* b2   = (const float*)d_in[14];
    const int* ids    = (const int*)d_in[15];
    const int* pidx   = (const int*)d_in[16];
    float* out = (float*)d_out;

    // Workspace layout (bytes):
    //   Gt:    [2][64][256][1024] f32 = 134217728
    //   allb:  [256][32][1024] bf16   =  16777216
    //   hx_bf: [2][256][32][512] bf16 =  16777216
    //   Wbf:   [2][2048][1024] bf16   =   8388608  (per-layer reuse)
    //   biasC: [2][2048] f32          =     16384
    //   mid:   [512][1024] f32        =   2097152
    //   ctr:   16
    char* ws = (char*)d_ws;
    float* Gt    = (float*)ws;
    u16*   allb  = (u16*)(ws + 134217728u);
    u16*   hx    = (u16*)(ws + 150994944u);
    u16*   Wbf   = (u16*)(ws + 167772160u);
    float* biasC = (float*)(ws + 176160768u);
    float* mid   = (float*)(ws + 176177152u);
    int*   ctr   = (int*)(ws + 178274304u);

    k_zero<<<dim3(1), dim3(4), 0, stream>>>(ctr);
    k_allb<<<dim3(NBS), dim3(256), 0, stream>>>(emb, ctx, pemb, ids, pidx, allb);

    // Layer 0
    k_wcvt<<<dim3(2 * NG), dim3(256), 0, stream>>>(Wih0, bih0, bhh0, Wbf, biasC);
    for (int d = 0; d < 2; ++d)
        k_gemm_m<<<dim3(NG / 128, NBS / 128), dim3(256), 0, stream>>>(
            allb, allb + 512, 1024, Wbf + (size_t)d * NG * GK, biasC + d * NG,
            Gt + (size_t)d * GT_DIR);
    k_lstm_f<<<dim3(2 * NWGD), dim3(256), 0, stream>>>(Gt, Whh0, hx, ctr);

    k_raw<<<dim3(NBS), dim3(256), 0, stream>>>(emb, ids, out);

    // Layer 1 (A = hx_bf, dir halves)
    k_wcvt<<<dim3(2 * NG), dim3(256), 0, stream>>>(Wih1, bih1, bhh1, Wbf, biasC);
    for (int d = 0; d < 2; ++d)
        k_gemm_m<<<dim3(NG / 128, NBS / 128), dim3(256), 0, stream>>>(
            hx, hx + (size_t)NS * NB * NHD, 512, Wbf + (size_t)d * NG * GK,
            biasC + d * NG, Gt + (size_t)d * GT_DIR);
    k_lstm_f<<<dim3(2 * NWGD), dim3(256), 0, stream>>>(Gt, Whh1, hx, ctr + 2);

    // MLP head at prompt rows
    k_mlp1<<<dim3(16, 8), dim3(256), 0, stream>>>(hx, pidx, W1, b1, mid);
    k_mlp2<<<dim3(16, 8), dim3(256), 0, stream>>>(mid, pidx, W2, b2, pemb, out);
}